// Round 4
// baseline (260.318 us; speedup 1.0000x reference)
//
#include <hip/hip_runtime.h>

// GRU with per-row sequence lengths. B=4096, T=200, I=64, H=128 (hardcoded).
// Output[b] = h after seq_lengths[b] steps from h0=0.
//
// Round-4 structure:
//  - Kernel 1: counting sort of rows by seq_length (1 block, LDS hist, perm
//    in d_ws). Rows grouped by similar length -> per-block Lmax ~= row length
//    (-43% total steps vs random grouping). Per-row outputs are bit-identical
//    regardless of grouping, so nondeterministic within-bin order is safe.
//  - Kernel 2: 512 blocks x 256 thr (4 waves), 8 sorted rows/block, 2
//    blocks/CU (de-phased barriers). Slice remap pairs long+short blocks per
//    CU. Wave owns 32 h-cols (96 gate cols, 36 MFMA/step), B-frags resident
//    in VGPRs. A-tile M=16 with rows 8..15 permanently zero.
//  - x staged in 8-step LDS ring chunks: global loads in 1 of 8 steps only,
//    issued top-of-step / LDS-written bottom-of-step -> __syncthreads()
//    vmcnt drain is ~free. __syncthreads for correct ordering (round-3 raw
//    barrier raced via compiler hoisting across s_barrier).

#define I_DIM 64
#define H_DIM 128
#define ROWS 8    // real batch rows per block
#define CH 8      // x-chunk steps
#define HP 136    // h-tile row stride in halves (128 + 8 pad -> 2-way max)
#define XP 72     // x-ring row stride in halves (64 + 8 pad -> 2-way max)

typedef _Float16 h8 __attribute__((ext_vector_type(8)));
typedef _Float16 h4 __attribute__((ext_vector_type(4)));
typedef float f4 __attribute__((ext_vector_type(4)));

__device__ __forceinline__ float fast_rcp(float x) {
    return __builtin_amdgcn_rcpf(x);
}
__device__ __forceinline__ float sigmoid_f(float x) {
    return fast_rcp(1.0f + __expf(-x));
}
__device__ __forceinline__ float tanh_f(float x) {
    return 1.0f - 2.0f * fast_rcp(__expf(2.0f * x) + 1.0f);
}

// ---- kernel 1: counting sort (ascending by seq_length), perm[pos] = row ----
__global__ __launch_bounds__(256)
void count_sort_kernel(const int* __restrict__ L, int* __restrict__ perm, int B) {
    __shared__ int hist[256];
    __shared__ int offs[256];
    const int tid = threadIdx.x;
    hist[tid] = 0;
    __syncthreads();
    for (int i = tid; i < B; i += 256) {
        int v = L[i]; v = v < 0 ? 0 : (v > 255 ? 255 : v);
        atomicAdd(&hist[v], 1);
    }
    __syncthreads();
    if (tid == 0) {
        int run = 0;
        for (int b = 0; b < 256; ++b) { offs[b] = run; run += hist[b]; }
    }
    __syncthreads();
    for (int i = tid; i < B; i += 256) {
        int v = L[i]; v = v < 0 ? 0 : (v > 255 ? 255 : v);
        int pos = atomicAdd(&offs[v], 1);
        perm[pos] = i;
    }
}

// ---- kernel 2: the GRU recurrence ----
__global__ __launch_bounds__(256, 2)
void gru_seq_kernel(const float* __restrict__ input,
                    const int* __restrict__ seq_lengths,
                    const float* __restrict__ W_ih,
                    const float* __restrict__ W_hh,
                    const float* __restrict__ b_ih,
                    const float* __restrict__ b_hh,
                    const int* __restrict__ perm,   // may be null -> identity
                    float* __restrict__ out,
                    int B, int T) {
    // h-tile (double-buffered) + x-ring (2 chunks x 8 steps); rows 8..15 stay 0
    __shared__ __align__(16) _Float16 h_lds[2][16][HP];
    __shared__ __align__(16) _Float16 x_lds[2][CH][16][XP];

    const int tid  = threadIdx.x;
    const int lane = tid & 63;
    const int w    = tid >> 6;     // wave 0..3
    const int lrow = lane & 15;    // MFMA A-row / C-col index
    const int kgrp = lane >> 4;    // 0..3

    // slice remap: pair long+short blocks on the (i, i+256) round-robin heuristic
    const int half  = gridDim.x >> 1;
    const int blk   = blockIdx.x;
    const int slice = (blk < half) ? blk : (gridDim.x - 1 - (blk - half));
    const int base  = slice * ROWS;

    // ---- per-lane mapped rows + sequence lengths ----
    int Lq[4], grq[4];
#pragma unroll
    for (int q = 0; q < 4; ++q) {
        int r  = kgrp * 4 + q;
        int gi = base + r;
        int gr = (r < ROWS && gi < B) ? (perm ? perm[gi] : gi) : -1;
        grq[q] = gr;
        Lq[q]  = (gr >= 0) ? seq_lengths[gr] : 0;
    }
    int Lmax = 0;
    for (int i = 0; i < ROWS; ++i) {
        int gi = base + i;
        if (gi < B) {
            int gr = perm ? perm[gi] : gi;
            int L = seq_lengths[gr];
            Lmax = max(Lmax, L);
        }
    }
    if (Lmax > T) Lmax = T;

    // ---- biases (C col = w*32 + tau*16 + lrow) ----
    float br[2], bz[2], bnh[2], bnx[2];
#pragma unroll
    for (int tau = 0; tau < 2; ++tau) {
        int c = w * 32 + tau * 16 + lrow;
        br[tau]  = b_ih[c] + b_hh[c];
        bz[tau]  = b_ih[H_DIM + c] + b_hh[H_DIM + c];
        bnh[tau] = b_hh[2 * H_DIM + c];
        bnx[tau] = b_ih[2 * H_DIM + c];
    }

    // ---- resident B-fragments (36 x h8 = 144 VGPR) ----
    h8 bw[36];
#pragma unroll
    for (int c = 0; c < 6; ++c) {
        const int gate = c >> 1, tau = c & 1;
        const int j = gate * H_DIM + w * 32 + tau * 16 + lrow;
#pragma unroll
        for (int kt = 0; kt < 6; ++kt) {
            const int kb = kt * 32 + kgrp * 8;
            const float* src = (kt < 4) ? (W_hh + j * H_DIM + kb)
                                        : (W_ih + j * I_DIM + (kb - H_DIM));
            f4 f0 = *(const f4*)(src);
            f4 f1 = *(const f4*)(src + 4);
            h8 v;
            v[0] = (_Float16)f0[0]; v[1] = (_Float16)f0[1];
            v[2] = (_Float16)f0[2]; v[3] = (_Float16)f0[3];
            v[4] = (_Float16)f1[0]; v[5] = (_Float16)f1[1];
            v[6] = (_Float16)f1[2]; v[7] = (_Float16)f1[3];
            bw[c * 6 + kt] = v;
        }
    }

    // ---- zero all LDS (phantom rows 8..15 must stay zero forever) ----
    {
        h8 z = h8{0, 0, 0, 0, 0, 0, 0, 0};
        h8* ph = (h8*)&h_lds[0][0][0];
        for (int i = tid; i < 2 * 16 * HP / 8; i += 256) ph[i] = z;
        h8* px = (h8*)&x_lds[0][0][0][0];
        for (int i = tid; i < 2 * CH * 16 * XP / 8; i += 256) px[i] = z;
    }
    __syncthreads();

    // ---- x chunk staging: thread -> (srow = tid>>5, 4 x f4 within 512-float slice)
    const int srow = tid >> 5;                    // 0..7
    const int gxr  = (base + srow < B) ? (perm ? perm[base + srow] : base + srow) : -1;
    const float* xsrc = (gxr >= 0) ? (input + (size_t)gxr * T * I_DIM) : input;
    const bool xok = (gxr >= 0);
    const int eoff = (tid & 31) * 4;              // element offset within slice
    const int si0  = (tid & 31) >> 4;             // s contribution from tid
    const int icol = (tid & 15) * 4;              // column within step

    // prologue: stage chunk 0 (steps 0..7) into slot 0
    if (Lmax > 0) {
        f4 xv[4];
#pragma unroll
        for (int j = 0; j < 4; ++j) {
            int s = si0 + 2 * j;
            xv[j] = f4{0.f, 0.f, 0.f, 0.f};
            if (xok && s < T) xv[j] = *(const f4*)(xsrc + (size_t)s * I_DIM + icol);
        }
#pragma unroll
        for (int j = 0; j < 4; ++j) {
            int s = si0 + 2 * j;
            h4 hv;
            hv[0] = (_Float16)xv[j][0]; hv[1] = (_Float16)xv[j][1];
            hv[2] = (_Float16)xv[j][2]; hv[3] = (_Float16)xv[j][3];
            *(h4*)&x_lds[0][s][srow][icol] = hv;
        }
    }
    __syncthreads();

    // fp32 master h (lane positions: row = kgrp*4+q, col = w*32+tau*16+lrow)
    float hreg[2][4]  = {{0.f, 0.f, 0.f, 0.f}, {0.f, 0.f, 0.f, 0.f}};
    float hnreg[2][4] = {{0.f, 0.f, 0.f, 0.f}, {0.f, 0.f, 0.f, 0.f}};

    for (int t = 0; t < Lmax; ++t) {
        const int cur = t & 1, nxt = cur ^ 1;
        const int xslot = (t >> 3) & 1;

        // issue next-chunk loads at top of the chunk-boundary step
        f4 xv[4];
        const bool do_stage = ((t & 7) == 0) && (t + CH < Lmax);
        if (do_stage) {
            const int t0 = t + CH;
#pragma unroll
            for (int j = 0; j < 4; ++j) {
                int s = si0 + 2 * j;
                xv[j] = f4{0.f, 0.f, 0.f, 0.f};
                if (xok && t0 + s < T) xv[j] = *(const f4*)(xsrc + (size_t)(t0 + s) * I_DIM + icol);
            }
        }

        // A-fragments: kt 0..3 from h-tile, kt 4..5 from x-ring
        h8 af[6];
#pragma unroll
        for (int kt = 0; kt < 4; ++kt)
            af[kt] = *(const h8*)&h_lds[cur][lrow][kt * 32 + kgrp * 8];
#pragma unroll
        for (int kt = 4; kt < 6; ++kt)
            af[kt] = *(const h8*)&x_lds[xslot][t & 7][lrow][(kt - 4) * 32 + kgrp * 8];

        f4 ar[2], az[2], anh_[2], anx_[2];
#pragma unroll
        for (int tau = 0; tau < 2; ++tau) {
            ar[tau]   = f4{br[tau], br[tau], br[tau], br[tau]};
            az[tau]   = f4{bz[tau], bz[tau], bz[tau], bz[tau]};
            anh_[tau] = f4{bnh[tau], bnh[tau], bnh[tau], bnh[tau]};
            anx_[tau] = f4{bnx[tau], bnx[tau], bnx[tau], bnx[tau]};
        }
        __builtin_amdgcn_s_setprio(1);
#pragma unroll
        for (int tau = 0; tau < 2; ++tau) {
#pragma unroll
            for (int kt = 0; kt < 6; ++kt)
                ar[tau] = __builtin_amdgcn_mfma_f32_16x16x32_f16(af[kt], bw[(0 + tau) * 6 + kt], ar[tau], 0, 0, 0);
#pragma unroll
            for (int kt = 0; kt < 6; ++kt)
                az[tau] = __builtin_amdgcn_mfma_f32_16x16x32_f16(af[kt], bw[(2 + tau) * 6 + kt], az[tau], 0, 0, 0);
#pragma unroll
            for (int kt = 0; kt < 4; ++kt)   // n-gate h-part (K 0..127)
                anh_[tau] = __builtin_amdgcn_mfma_f32_16x16x32_f16(af[kt], bw[(4 + tau) * 6 + kt], anh_[tau], 0, 0, 0);
#pragma unroll
            for (int kt = 4; kt < 6; ++kt)   // n-gate x-part (K 128..191)
                anx_[tau] = __builtin_amdgcn_mfma_f32_16x16x32_f16(af[kt], bw[(4 + tau) * 6 + kt], anx_[tau], 0, 0, 0);
        }
        __builtin_amdgcn_s_setprio(0);

        // gate math (col = w*32+tau*16+lrow, row = kgrp*4+q)
#pragma unroll
        for (int tau = 0; tau < 2; ++tau) {
#pragma unroll
            for (int q = 0; q < 4; ++q) {
                float r    = sigmoid_f(ar[tau][q]);
                float z    = sigmoid_f(az[tau][q]);
                float n    = tanh_f(anx_[tau][q] + r * anh_[tau][q]);
                float h    = hreg[tau][q];
                float hnew = n + z * (h - n);
                hreg[tau][q] = hnew;
                if (t < Lq[q]) hnreg[tau][q] = hnew;   // capture while t+1 <= L
            }
        }

        // write h(t+1) into buf[nxt]; rows 0..7 only
        if (kgrp < 2) {
#pragma unroll
            for (int tau = 0; tau < 2; ++tau)
#pragma unroll
                for (int q = 0; q < 4; ++q)
                    h_lds[nxt][kgrp * 4 + q][w * 32 + tau * 16 + lrow] = (_Float16)hreg[tau][q];
        }
        // write next x-chunk (loads issued at top of this step)
        if (do_stage) {
            const int wslot = xslot ^ 1;
#pragma unroll
            for (int j = 0; j < 4; ++j) {
                int s = si0 + 2 * j;
                h4 hv;
                hv[0] = (_Float16)xv[j][0]; hv[1] = (_Float16)xv[j][1];
                hv[2] = (_Float16)xv[j][2]; hv[3] = (_Float16)xv[j][3];
                *(h4*)&x_lds[wslot][s][srow][icol] = hv;
            }
        }
        __syncthreads();
    }

    // ---- store hn (rows 0..7 only, permuted scatter) ----
    if (kgrp < 2) {
#pragma unroll
        for (int tau = 0; tau < 2; ++tau) {
#pragma unroll
            for (int q = 0; q < 4; ++q) {
                int gr = grq[q];
                if (gr >= 0) out[(size_t)gr * H_DIM + w * 32 + tau * 16 + lrow] = hnreg[tau][q];
            }
        }
    }
}

extern "C" void kernel_launch(void* const* d_in, const int* in_sizes, int n_in,
                              void* d_out, int out_size, void* d_ws, size_t ws_size,
                              hipStream_t stream) {
    const float* input = (const float*)d_in[0];
    const int*   seq   = (const int*)d_in[1];
    const float* W_ih  = (const float*)d_in[2];
    const float* W_hh  = (const float*)d_in[3];
    const float* b_ih  = (const float*)d_in[4];
    const float* b_hh  = (const float*)d_in[5];
    float* out = (float*)d_out;

    const int B = in_sizes[1];
    const int T = in_sizes[0] / (B * I_DIM);

    int* perm = nullptr;
    if (ws_size >= (size_t)B * sizeof(int)) {
        perm = (int*)d_ws;
        count_sort_kernel<<<1, 256, 0, stream>>>(seq, perm, B);
    }

    const int grid = (B + ROWS - 1) / ROWS;
    gru_seq_kernel<<<grid, 256, 0, stream>>>(input, seq, W_ih, W_hh, b_ih, b_hh, perm, out, B, T);
}

// Round 5
// 158.886 us; speedup vs baseline: 1.6384x; 1.6384x over previous
//
#include <hip/hip_runtime.h>

// GRU with per-row sequence lengths. B=4096, T=200, I=64, H=128 (hardcoded).
// Output[b] = h after seq_lengths[b] steps from h0=0.
//
// Round-5 structure: 256 blocks x 512 threads (8 waves, 2/SIMD), 16 real
// rows/block (r2 base, measured spill-free). Wave owns 16 h-cols (48 gate
// cols): 12 h-part MFMA + 6 x-part MFMA per step, B-frags (18 x h8 = 72
// VGPR) resident. Changes vs r2:
//  - x staged in 8-step LDS ring chunks -> __syncthreads vmcnt(0) drain is
//    free in 7/8 steps (r2 drained a fresh HBM load EVERY step).
//  - x-part gate contributions (W_ih . x(t+1) + biases) computed one step
//    ahead (independent of h) and used as the h-chain accumulator init ->
//    critical phase is only 4 h-frag ds_reads + 12 MFMA + gate VALU.
//  - __syncthreads for ordering (r3 raw-barrier raced); setprio around MFMA.

#define I_DIM 64
#define H_DIM 128
#define CH 8     // x-chunk steps
#define HP 136   // h-tile row stride in halves (128 + 8 pad)
#define XP 72    // x-ring row stride in halves (64 + 8 pad)

typedef _Float16 h8 __attribute__((ext_vector_type(8)));
typedef _Float16 h4 __attribute__((ext_vector_type(4)));
typedef float f4 __attribute__((ext_vector_type(4)));

__device__ __forceinline__ float fast_rcp(float x) {
    return __builtin_amdgcn_rcpf(x);
}
__device__ __forceinline__ float sigmoid_f(float x) {
    return fast_rcp(1.0f + __expf(-x));
}
__device__ __forceinline__ float tanh_f(float x) {
    return 1.0f - 2.0f * fast_rcp(__expf(2.0f * x) + 1.0f);
}

__global__ __launch_bounds__(512, 2)
void gru_seq_kernel(const float* __restrict__ input,
                    const int* __restrict__ seq_lengths,
                    const float* __restrict__ W_ih,
                    const float* __restrict__ W_hh,
                    const float* __restrict__ b_ih,
                    const float* __restrict__ b_hh,
                    float* __restrict__ out,
                    int B, int T) {
    __shared__ __align__(16) _Float16 h_lds[2][16][HP];          // double-buffered h
    __shared__ __align__(16) _Float16 x_lds[2][CH][16][XP];      // x ring (2 chunks)

    const int tid  = threadIdx.x;
    const int lane = tid & 63;
    const int w    = tid >> 6;     // wave 0..7
    const int base = blockIdx.x * 16;

    const int lrow = lane & 15;    // MFMA A-row / C-col index
    const int kgrp = lane >> 4;    // 0..3 (k-slice for A/B frags; row-group for C)

    // ---- sequence lengths ----
    int Lq[4];
#pragma unroll
    for (int q = 0; q < 4; ++q) {
        int gr = base + kgrp * 4 + q;
        Lq[q] = (gr < B) ? seq_lengths[gr] : 0;
    }
    int Lmax = 0;
    for (int i = 0; i < 16; ++i) {
        int gr = base + i;
        int L = (gr < B) ? seq_lengths[gr] : 0;
        Lmax = max(Lmax, L);
    }
    if (Lmax > T) Lmax = T;

    // ---- biases (C col = w*16 + lrow) ----
    const int c0 = w * 16 + lrow;
    const float br  = b_ih[c0] + b_hh[c0];
    const float bz  = b_ih[H_DIM + c0] + b_hh[H_DIM + c0];
    const float bnh = b_hh[2 * H_DIM + c0];
    const float bnx = b_ih[2 * H_DIM + c0];

    // ---- resident B-fragments: Wcat[j][k], k 0..127 = W_hh, 128..191 = W_ih.
    // Frag (gate,kt): lane holds Wcat[j][kb..kb+7], j = gate*128 + c0,
    // kb = kt*32 + kgrp*8. 18 frags = 72 VGPR.
    h8 bw[18];
#pragma unroll
    for (int gate = 0; gate < 3; ++gate) {
        const int j = gate * H_DIM + c0;
#pragma unroll
        for (int kt = 0; kt < 6; ++kt) {
            const int kb = kt * 32 + kgrp * 8;
            const float* src = (kt < 4) ? (W_hh + j * H_DIM + kb)
                                        : (W_ih + j * I_DIM + (kb - H_DIM));
            f4 f0 = *(const f4*)(src);
            f4 f1 = *(const f4*)(src + 4);
            h8 v;
            v[0] = (_Float16)f0[0]; v[1] = (_Float16)f0[1];
            v[2] = (_Float16)f0[2]; v[3] = (_Float16)f0[3];
            v[4] = (_Float16)f1[0]; v[5] = (_Float16)f1[1];
            v[6] = (_Float16)f1[2]; v[7] = (_Float16)f1[3];
            bw[gate * 6 + kt] = v;
        }
    }

    // ---- zero h buffer 0 (h(0) = 0) ----
    {
        int idx = tid * 4;             // 16*128 = 2048 halves / 512 threads
        int r = idx >> 7, cc = idx & 127;
        *(h4*)&h_lds[0][r][cc] = h4{0, 0, 0, 0};
    }

    // ---- x chunk staging layout: 32 threads/row; thread covers 4 steps ----
    const int srow = tid >> 5;                    // 0..15
    const int si0  = (tid & 31) >> 4;             // 0..1
    const int icol = (tid & 15) * 4;              // 0,4,..,60
    const int gxr  = base + srow;
    const float* xsrc = input + (size_t)gxr * T * I_DIM;
    const bool xok = (gxr < B);

    // prologue: stage chunk 0 (steps 0..7) into slot 0
    if (Lmax > 0) {
        f4 xv[4];
#pragma unroll
        for (int j = 0; j < 4; ++j) {
            int s = si0 + 2 * j;
            xv[j] = f4{0.f, 0.f, 0.f, 0.f};
            if (xok && s < T) xv[j] = *(const f4*)(xsrc + (size_t)s * I_DIM + icol);
        }
#pragma unroll
        for (int j = 0; j < 4; ++j) {
            int s = si0 + 2 * j;
            h4 hv;
            hv[0] = (_Float16)xv[j][0]; hv[1] = (_Float16)xv[j][1];
            hv[2] = (_Float16)xv[j][2]; hv[3] = (_Float16)xv[j][3];
            *(h4*)&x_lds[0][s][srow][icol] = hv;
        }
    }
    __syncthreads();

    // ---- x-part accumulators for step 0 (gx + biases) ----
    f4 arx  = f4{br, br, br, br};
    f4 azx  = f4{bz, bz, bz, bz};
    f4 anxx = f4{bnx, bnx, bnx, bnx};
    if (Lmax > 0) {
        h8 xg0 = *(const h8*)&x_lds[0][0][lrow][kgrp * 8];
        h8 xg1 = *(const h8*)&x_lds[0][0][lrow][32 + kgrp * 8];
        arx  = __builtin_amdgcn_mfma_f32_16x16x32_f16(xg0, bw[0 * 6 + 4], arx, 0, 0, 0);
        arx  = __builtin_amdgcn_mfma_f32_16x16x32_f16(xg1, bw[0 * 6 + 5], arx, 0, 0, 0);
        azx  = __builtin_amdgcn_mfma_f32_16x16x32_f16(xg0, bw[1 * 6 + 4], azx, 0, 0, 0);
        azx  = __builtin_amdgcn_mfma_f32_16x16x32_f16(xg1, bw[1 * 6 + 5], azx, 0, 0, 0);
        anxx = __builtin_amdgcn_mfma_f32_16x16x32_f16(xg0, bw[2 * 6 + 4], anxx, 0, 0, 0);
        anxx = __builtin_amdgcn_mfma_f32_16x16x32_f16(xg1, bw[2 * 6 + 5], anxx, 0, 0, 0);
    }

    // fp32 master h (lane positions: row = kgrp*4+q, col = c0)
    float hreg[4]  = {0.f, 0.f, 0.f, 0.f};
    float hnreg[4] = {0.f, 0.f, 0.f, 0.f};

    for (int t = 0; t < Lmax; ++t) {
        const int cur = t & 1, nxt = cur ^ 1;

        // stage loads for chunk t/8 + 1 (issued at top; ds-written at bottom;
        // the barrier's vmcnt(0) drain is free in 7 of 8 steps)
        f4 xv[4];
        const bool do_stage = ((t & 7) == 0) && (t + CH < Lmax);
        if (do_stage) {
            const int t0 = t + CH;
#pragma unroll
            for (int j = 0; j < 4; ++j) {
                int s = si0 + 2 * j;
                xv[j] = f4{0.f, 0.f, 0.f, 0.f};
                if (xok && t0 + s < T) xv[j] = *(const f4*)(xsrc + (size_t)(t0 + s) * I_DIM + icol);
            }
        }

        // h A-fragments (kt 0..3)
        h8 af0 = *(const h8*)&h_lds[cur][lrow][0 * 32 + kgrp * 8];
        h8 af1 = *(const h8*)&h_lds[cur][lrow][1 * 32 + kgrp * 8];
        h8 af2 = *(const h8*)&h_lds[cur][lrow][2 * 32 + kgrp * 8];
        h8 af3 = *(const h8*)&h_lds[cur][lrow][3 * 32 + kgrp * 8];
        // x A-fragments for step t+1 (ring slot is stable; independent work)
        const int slot1 = ((t + 1) >> 3) & 1;
        const int ss1   = (t + 1) & 7;
        h8 xg0 = *(const h8*)&x_lds[slot1][ss1][lrow][kgrp * 8];
        h8 xg1 = *(const h8*)&x_lds[slot1][ss1][lrow][32 + kgrp * 8];

        // h-part chains, init'd from the x-part accumulators computed last step
        f4 ar   = arx;
        f4 az   = azx;
        f4 anxc = anxx;
        f4 anh  = f4{bnh, bnh, bnh, bnh};
        __builtin_amdgcn_s_setprio(1);
        ar  = __builtin_amdgcn_mfma_f32_16x16x32_f16(af0, bw[0 * 6 + 0], ar, 0, 0, 0);
        ar  = __builtin_amdgcn_mfma_f32_16x16x32_f16(af1, bw[0 * 6 + 1], ar, 0, 0, 0);
        ar  = __builtin_amdgcn_mfma_f32_16x16x32_f16(af2, bw[0 * 6 + 2], ar, 0, 0, 0);
        ar  = __builtin_amdgcn_mfma_f32_16x16x32_f16(af3, bw[0 * 6 + 3], ar, 0, 0, 0);
        az  = __builtin_amdgcn_mfma_f32_16x16x32_f16(af0, bw[1 * 6 + 0], az, 0, 0, 0);
        az  = __builtin_amdgcn_mfma_f32_16x16x32_f16(af1, bw[1 * 6 + 1], az, 0, 0, 0);
        az  = __builtin_amdgcn_mfma_f32_16x16x32_f16(af2, bw[1 * 6 + 2], az, 0, 0, 0);
        az  = __builtin_amdgcn_mfma_f32_16x16x32_f16(af3, bw[1 * 6 + 3], az, 0, 0, 0);
        anh = __builtin_amdgcn_mfma_f32_16x16x32_f16(af0, bw[2 * 6 + 0], anh, 0, 0, 0);
        anh = __builtin_amdgcn_mfma_f32_16x16x32_f16(af1, bw[2 * 6 + 1], anh, 0, 0, 0);
        anh = __builtin_amdgcn_mfma_f32_16x16x32_f16(af2, bw[2 * 6 + 2], anh, 0, 0, 0);
        anh = __builtin_amdgcn_mfma_f32_16x16x32_f16(af3, bw[2 * 6 + 3], anh, 0, 0, 0);
        // x-part for step t+1 (independent of everything above)
        f4 nrx  = f4{br, br, br, br};
        f4 nzx  = f4{bz, bz, bz, bz};
        f4 nnx  = f4{bnx, bnx, bnx, bnx};
        nrx = __builtin_amdgcn_mfma_f32_16x16x32_f16(xg0, bw[0 * 6 + 4], nrx, 0, 0, 0);
        nrx = __builtin_amdgcn_mfma_f32_16x16x32_f16(xg1, bw[0 * 6 + 5], nrx, 0, 0, 0);
        nzx = __builtin_amdgcn_mfma_f32_16x16x32_f16(xg0, bw[1 * 6 + 4], nzx, 0, 0, 0);
        nzx = __builtin_amdgcn_mfma_f32_16x16x32_f16(xg1, bw[1 * 6 + 5], nzx, 0, 0, 0);
        nnx = __builtin_amdgcn_mfma_f32_16x16x32_f16(xg0, bw[2 * 6 + 4], nnx, 0, 0, 0);
        nnx = __builtin_amdgcn_mfma_f32_16x16x32_f16(xg1, bw[2 * 6 + 5], nnx, 0, 0, 0);
        __builtin_amdgcn_s_setprio(0);
        arx = nrx; azx = nzx; anxx = nnx;

        // gate math (C layout: col = c0, row = kgrp*4+q)
#pragma unroll
        for (int q = 0; q < 4; ++q) {
            float r    = sigmoid_f(ar[q]);
            float z    = sigmoid_f(az[q]);
            float n    = tanh_f(anxc[q] + r * anh[q]);
            float h    = hreg[q];
            float hnew = n + z * (h - n);
            hreg[q] = hnew;
            if (t < Lq[q]) hnreg[q] = hnew;   // capture while t+1 <= L
        }

        // write h(t+1) into buf[nxt] (all 16 rows covered: kgrp*4+q x 8 waves' cols)
#pragma unroll
        for (int q = 0; q < 4; ++q)
            h_lds[nxt][kgrp * 4 + q][c0] = (_Float16)hreg[q];
        // write next x-chunk into the other ring slot
        if (do_stage) {
            const int wslot = ((t >> 3) & 1) ^ 1;
#pragma unroll
            for (int j = 0; j < 4; ++j) {
                int s = si0 + 2 * j;
                h4 hv;
                hv[0] = (_Float16)xv[j][0]; hv[1] = (_Float16)xv[j][1];
                hv[2] = (_Float16)xv[j][2]; hv[3] = (_Float16)xv[j][3];
                *(h4*)&x_lds[wslot][s][srow][icol] = hv;
            }
        }
        __syncthreads();
    }

    // ---- store hn ----
#pragma unroll
    for (int q = 0; q < 4; ++q) {
        int gr = base + kgrp * 4 + q;
        if (gr < B) out[(size_t)gr * H_DIM + c0] = hnreg[q];
    }
}

extern "C" void kernel_launch(void* const* d_in, const int* in_sizes, int n_in,
                              void* d_out, int out_size, void* d_ws, size_t ws_size,
                              hipStream_t stream) {
    const float* input = (const float*)d_in[0];
    const int*   seq   = (const int*)d_in[1];
    const float* W_ih  = (const float*)d_in[2];
    const float* W_hh  = (const float*)d_in[3];
    const float* b_ih  = (const float*)d_in[4];
    const float* b_hh  = (const float*)d_in[5];
    float* out = (float*)d_out;

    const int B = in_sizes[1];
    const int T = in_sizes[0] / (B * I_DIM);

    const int grid = (B + 15) / 16;
    gru_seq_kernel<<<grid, 512, 0, stream>>>(input, seq, W_ih, W_hh, b_ih, b_hh, out, B, T);
}